// Round 1
// baseline (424.605 us; speedup 1.0000x reference)
//
#include <hip/hip_runtime.h>
#include <hip/hip_bf16.h>
#include <math.h>

#define NN 4096
#define DD 128
#define CAPN 32
#define CAPM 32
#define CAPR 256

// ---------------------------------------------------------------------------
// sq norms of rows: one wave per row, blockIdx.y selects which input
__global__ __launch_bounds__(64) void sqnorm_kernel(
    const float* __restrict__ Xe, const float* __restrict__ Xz,
    float* __restrict__ sqe, float* __restrict__ sqz) {
  int row = blockIdx.x;
  const float* X = blockIdx.y ? Xz : Xe;
  float* sq = blockIdx.y ? sqz : sqe;
  int lane = threadIdx.x;
  float v0 = X[(size_t)row * DD + lane];
  float v1 = X[(size_t)row * DD + 64 + lane];
  float s = v0 * v0 + v1 * v1;
  for (int off = 32; off; off >>= 1) s += __shfl_down(s, off);
  if (lane == 0) sq[row] = s;
}

// ---------------------------------------------------------------------------
// Gram -> distance matrices. Triangular block decomposition (bx<=by),
// each block computes a 64x64 tile and writes it and its transpose.
// blockIdx.z==0: d_ema = sqrt(max(d2,0)+1e-12)
// blockIdx.z==1: dist  = sqrt(d_ema_like + 1e-9)
__global__ __launch_bounds__(256) void gram_kernel(
    const float* __restrict__ Xe, const float* __restrict__ sqe,
    const float* __restrict__ Xz, const float* __restrict__ sqz,
    float* __restrict__ de, float* __restrict__ dz) {
  __shared__ float As[64][132];
  __shared__ float Bs[64][132];
  int b = blockIdx.x;
  int by = (int)((sqrtf(8.0f * (float)b + 1.0f) - 1.0f) * 0.5f);
  while ((by + 1) * (by + 2) / 2 <= b) by++;
  while (by * (by + 1) / 2 > b) by--;
  int bx = b - by * (by + 1) / 2;  // bx <= by
  const float* X  = blockIdx.z ? Xz : Xe;
  const float* sq = blockIdx.z ? sqz : sqe;
  float* out      = blockIdx.z ? dz : de;
  int I = bx * 64, J = by * 64;
  int t = threadIdx.x;
  // load 64 rows x 128 f32 for each side (float4-coalesced)
  for (int c = t; c < 64 * 32; c += 256) {
    int r = c >> 5, q = c & 31;
    reinterpret_cast<float4*>(&As[r][0])[q] =
        reinterpret_cast<const float4*>(X + (size_t)(I + r) * DD)[q];
    reinterpret_cast<float4*>(&Bs[r][0])[q] =
        reinterpret_cast<const float4*>(X + (size_t)(J + r) * DD)[q];
  }
  __syncthreads();
  int tx = t & 15, ty = t >> 4;
  int i0 = ty * 4, j0 = tx * 4;
  float acc[4][4] = {};
  for (int k = 0; k < DD; k += 4) {
    float4 a0 = *reinterpret_cast<const float4*>(&As[i0 + 0][k]);
    float4 a1 = *reinterpret_cast<const float4*>(&As[i0 + 1][k]);
    float4 a2 = *reinterpret_cast<const float4*>(&As[i0 + 2][k]);
    float4 a3 = *reinterpret_cast<const float4*>(&As[i0 + 3][k]);
    float4 b0 = *reinterpret_cast<const float4*>(&Bs[j0 + 0][k]);
    float4 b1 = *reinterpret_cast<const float4*>(&Bs[j0 + 1][k]);
    float4 b2 = *reinterpret_cast<const float4*>(&Bs[j0 + 2][k]);
    float4 b3 = *reinterpret_cast<const float4*>(&Bs[j0 + 3][k]);
    float4 av[4] = {a0, a1, a2, a3};
    float4 bv[4] = {b0, b1, b2, b3};
#pragma unroll
    for (int ii = 0; ii < 4; ++ii)
#pragma unroll
      for (int jj = 0; jj < 4; ++jj)
        acc[ii][jj] += av[ii].x * bv[jj].x + av[ii].y * bv[jj].y +
                       av[ii].z * bv[jj].z + av[ii].w * bv[jj].w;
  }
  int mode = blockIdx.z;
  float dv[4][4];
#pragma unroll
  for (int ii = 0; ii < 4; ++ii) {
#pragma unroll
    for (int jj = 0; jj < 4; ++jj) {
      int gi = I + i0 + ii, gj = J + j0 + jj;
      float d2 = (gi == gj) ? 0.0f : (sq[gi] + sq[gj] - 2.0f * acc[ii][jj]);
      float d = sqrtf(fmaxf(d2, 0.0f) + 1e-12f);
      if (mode) d = sqrtf(d + 1e-9f);
      dv[ii][jj] = d;
    }
  }
#pragma unroll
  for (int ii = 0; ii < 4; ++ii) {
    float4 v = make_float4(dv[ii][0], dv[ii][1], dv[ii][2], dv[ii][3]);
    *reinterpret_cast<float4*>(out + (size_t)(I + i0 + ii) * NN + J + j0) = v;
  }
#pragma unroll
  for (int jj = 0; jj < 4; ++jj) {
    float4 v = make_float4(dv[0][jj], dv[1][jj], dv[2][jj], dv[3][jj]);
    *reinterpret_cast<float4*>(out + (size_t)(J + j0 + jj) * NN + I + i0) = v;
  }
}

// ---------------------------------------------------------------------------
// per-row 5th smallest of d_ema
__global__ __launch_bounds__(256) void kth_kernel(const float* __restrict__ de,
                                                  float* __restrict__ kth) {
  __shared__ float lds[256][5];
  int row = blockIdx.x, t = threadIdx.x;
  const float* r = de + (size_t)row * NN;
  float best[5] = {3.4e38f, 3.4e38f, 3.4e38f, 3.4e38f, 3.4e38f};
  for (int c = t; c < NN; c += 256) {
    float v = r[c];
    if (v < best[4]) {
      best[4] = v;
#pragma unroll
      for (int q = 4; q > 0; --q)
        if (best[q] < best[q - 1]) {
          float tmp = best[q]; best[q] = best[q - 1]; best[q - 1] = tmp;
        }
    }
  }
#pragma unroll
  for (int q = 0; q < 5; ++q) lds[t][q] = best[q];
  __syncthreads();
  for (int s = 128; s >= 1; s >>= 1) {
    if (t < s) {
      float a[5], b[5], o[5];
#pragma unroll
      for (int q = 0; q < 5; ++q) { a[q] = lds[t][q]; b[q] = lds[t + s][q]; }
      int ia = 0, ib = 0;
#pragma unroll
      for (int q = 0; q < 5; ++q) o[q] = (a[ia] <= b[ib]) ? a[ia++] : b[ib++];
#pragma unroll
      for (int q = 0; q < 5; ++q) lds[t][q] = o[q];
    }
    __syncthreads();
  }
  if (t == 0) kth[row] = lds[0][4];
}

// ---------------------------------------------------------------------------
// row means of dist
__global__ __launch_bounds__(256) void rowmean_kernel(
    const float* __restrict__ dz, float* __restrict__ rowmean) {
  __shared__ double lds[256];
  int row = blockIdx.x, t = threadIdx.x;
  const float4* r = reinterpret_cast<const float4*>(dz + (size_t)row * NN);
  double s = 0;
  for (int c = t; c < NN / 4; c += 256) {
    float4 v = r[c];
    s += (double)v.x + v.y + v.z + v.w;
  }
  lds[t] = s;
  __syncthreads();
  for (int st = 128; st; st >>= 1) {
    if (t < st) lds[t] += lds[t + st];
    __syncthreads();
  }
  if (!t) rowmean[row] = (float)(lds[0] / NN);
}

// ---------------------------------------------------------------------------
// neighbor lists: nbr[j] = {i : d_ema[j,i] <= kth[j]} (= kNN set of j)
// also reverse lists rev[i] = {j : i in kNN(j)}; revcnt = rowsum(mask)
__global__ __launch_bounds__(64) void nbr_kernel(
    const float* __restrict__ de, const float* __restrict__ kth,
    int* __restrict__ nbr, int* __restrict__ nbrcnt,
    int* __restrict__ rev, int* __restrict__ revcnt) {
  int j = blockIdx.x;
  int lane = threadIdx.x;
  float kj = kth[j];
  __shared__ int cnt;
  if (lane == 0) cnt = 0;
  __syncthreads();
  const float* r = de + (size_t)j * NN;
  for (int i = lane; i < NN; i += 64) {
    if (r[i] <= kj) {
      int p = atomicAdd(&cnt, 1);
      if (p < CAPN) nbr[j * CAPN + p] = i;
      int q = atomicAdd(&revcnt[i], 1);
      if (q < CAPR) rev[(size_t)i * CAPR + q] = j;
    }
  }
  __syncthreads();
  if (lane == 0) nbrcnt[j] = min(cnt, CAPN);
}

// ---------------------------------------------------------------------------
// mutual lists: mut[k] = {j : j in kNN(k) and k in kNN(j)}  (rowsum(R))
__global__ __launch_bounds__(64) void mut_kernel(
    const int* __restrict__ nbr, const int* __restrict__ nbrcnt,
    int* __restrict__ mut, int* __restrict__ mutcnt) {
  int k = blockIdx.x;
  int lane = threadIdx.x;
  __shared__ int cnt;
  if (lane == 0) cnt = 0;
  __syncthreads();
  int ck = nbrcnt[k];
  if (lane < ck) {
    int j = nbr[k * CAPN + lane];
    int cj = nbrcnt[j];
    bool found = false;
    for (int q = 0; q < cj; ++q)
      if (nbr[j * CAPN + q] == k) { found = true; break; }
    if (found) {
      int p = atomicAdd(&cnt, 1);
      if (p < CAPM) mut[k * CAPM + p] = j;
    }
  }
  __syncthreads();
  if (lane == 0) mutcnt[k] = min(cnt, CAPM);
}

// ---------------------------------------------------------------------------
// sparse contribution: T = sum_{i,j} sim2[i,j]*abar[i,j]
//   = sum_i (1/(rs_m[i]*rs_R[i])) sum_{l in Rev(i)} sum_{k in kNN(l)}
//       sum_{j in mut(k)} abar[i,j]
__global__ __launch_bounds__(64) void sparse_kernel(
    const int* __restrict__ nbr, const int* __restrict__ nbrcnt,
    const int* __restrict__ rev, const int* __restrict__ revcnt,
    const int* __restrict__ mut, const int* __restrict__ mutcnt,
    const float* __restrict__ dz, const float* __restrict__ rowmean,
    double* __restrict__ acc) {
  int i = blockIdx.x, lane = threadIdx.x;
  int rm = revcnt[i];
  int rr = mutcnt[i];
  float inv_i = 1.0f / rowmean[i];
  const float* dzi = dz + (size_t)i * NN;
  double s = 0.0;
  int rcap = min(rm, CAPR);
  for (int li = lane; li < rcap; li += 64) {
    int l = rev[(size_t)i * CAPR + li];
    int cl = nbrcnt[l];
    for (int q = 0; q < cl; ++q) {
      int k = nbr[l * CAPN + q];
      int cm = mutcnt[k];
      for (int w = 0; w < cm; ++w) {
        int j = mut[k * CAPM + w];
        float dd = dzi[j];
        float d1 = dd * inv_i;           // delta[i,j]
        float d2 = dd / rowmean[j];      // delta[j,i]
        float r1 = fmaxf(1.0f - d1, 0.0f);
        float r2 = fmaxf(1.0f - d2, 0.0f);
        s += 0.5 * ((double)(d1 * d1 - r1 * r1) + (double)(d2 * d2 - r2 * r2));
      }
    }
  }
  for (int off = 32; off; off >>= 1) s += __shfl_down(s, off);
  if (lane == 0 && rm > 0 && rr > 0)
    atomicAdd(acc + 1, s / ((double)rm * (double)rr));
}

// ---------------------------------------------------------------------------
// dense pass: sum_{i,j} 0.5*exp(-d_ema)*a + relu(1-delta)^2
__global__ __launch_bounds__(256) void dense_kernel(
    const float* __restrict__ de, const float* __restrict__ dz,
    const float* __restrict__ rowmean, double* __restrict__ acc) {
  __shared__ double lds[256];
  int b = blockIdx.x;
  int row = b >> 1;
  int base = (b & 1) * 2048;
  float inv = 1.0f / rowmean[row];
  const float4* pe = reinterpret_cast<const float4*>(de + (size_t)row * NN + base);
  const float4* pz = reinterpret_cast<const float4*>(dz + (size_t)row * NN + base);
  int t = threadIdx.x;
  float4 e4[2], z4[2];
  e4[0] = pe[t * 2]; e4[1] = pe[t * 2 + 1];
  z4[0] = pz[t * 2]; z4[1] = pz[t * 2 + 1];
  float ev[8] = {e4[0].x, e4[0].y, e4[0].z, e4[0].w, e4[1].x, e4[1].y, e4[1].z, e4[1].w};
  float zv[8] = {z4[0].x, z4[0].y, z4[0].z, z4[0].w, z4[1].x, z4[1].y, z4[1].z, z4[1].w};
  double s = 0;
#pragma unroll
  for (int q = 0; q < 8; ++q) {
    float del = zv[q] * inv;
    float rr = fmaxf(1.0f - del, 0.0f);
    float a = del * del - rr * rr;
    s += (double)(0.5f * expf(-ev[q]) * a + rr * rr);
  }
  lds[t] = s;
  __syncthreads();
  for (int st = 128; st; st >>= 1) {
    if (t < st) lds[t] += lds[t + st];
    __syncthreads();
  }
  if (!t) atomicAdd(acc, lds[0]);
}

// ---------------------------------------------------------------------------
__global__ void init_kernel(int* __restrict__ revcnt, double* __restrict__ acc) {
  int t = blockIdx.x * 256 + threadIdx.x;
  if (t < NN) revcnt[t] = 0;
  if (t < 2) acc[t] = 0.0;
}

__global__ void finalize_kernel(const double* __restrict__ acc,
                                float* __restrict__ out) {
  out[0] = (float)((acc[0] + 0.5 * acc[1]) / (double)NN);
}

// ---------------------------------------------------------------------------
extern "C" void kernel_launch(void* const* d_in, const int* in_sizes, int n_in,
                              void* d_out, int out_size, void* d_ws, size_t ws_size,
                              hipStream_t stream) {
  const float* z  = (const float*)d_in[0];
  const float* ze = (const float*)d_in[1];
  float* out = (float*)d_out;

  char* w = (char*)d_ws;
  size_t SZ = (size_t)NN * NN * 4;
  float* de = (float*)w;
  float* dz = (float*)(w + SZ);
  size_t off = 2 * SZ;
  float* sqe = (float*)(w + off); off += NN * 4;
  float* sqz = (float*)(w + off); off += NN * 4;
  float* kth = (float*)(w + off); off += NN * 4;
  float* rmean = (float*)(w + off); off += NN * 4;
  double* acc = (double*)(w + off); off += 256;
  int* nbrcnt = (int*)(w + off); off += NN * 4;
  int* mutcnt = (int*)(w + off); off += NN * 4;
  int* revcnt = (int*)(w + off); off += NN * 4;
  int* nbr = (int*)(w + off); off += (size_t)NN * CAPN * 4;
  int* mutl = (int*)(w + off); off += (size_t)NN * CAPM * 4;
  int* rev = (int*)(w + off); off += (size_t)NN * CAPR * 4;

  init_kernel<<<dim3((NN + 255) / 256), 256, 0, stream>>>(revcnt, acc);
  sqnorm_kernel<<<dim3(NN, 2), 64, 0, stream>>>(ze, z, sqe, sqz);
  gram_kernel<<<dim3(2080, 1, 2), 256, 0, stream>>>(ze, sqe, z, sqz, de, dz);
  kth_kernel<<<NN, 256, 0, stream>>>(de, kth);
  rowmean_kernel<<<NN, 256, 0, stream>>>(dz, rmean);
  nbr_kernel<<<NN, 64, 0, stream>>>(de, kth, nbr, nbrcnt, rev, revcnt);
  mut_kernel<<<NN, 64, 0, stream>>>(nbr, nbrcnt, mutl, mutcnt);
  sparse_kernel<<<NN, 64, 0, stream>>>(nbr, nbrcnt, rev, revcnt, mutl, mutcnt,
                                       dz, rmean, acc);
  dense_kernel<<<NN * 2, 256, 0, stream>>>(de, dz, rmean, acc);
  finalize_kernel<<<1, 1, 0, stream>>>(acc, out);
}

// Round 2
// 207.206 us; speedup vs baseline: 2.0492x; 2.0492x over previous
//
#include <hip/hip_runtime.h>
#include <hip/hip_bf16.h>
#include <math.h>

#define NN 4096
#define DD 128
#define CAPN 32
#define CAPM 32
#define CAPR 256

typedef _Float16 f16x8 __attribute__((ext_vector_type(8)));
typedef float f32x4 __attribute__((ext_vector_type(4)));

// ---------------------------------------------------------------------------
// convert f32 -> fp16 copies + sq norms computed FROM THE ROUNDED values
// (so d2 = sq_i + sq_j - 2*G_fp16 == sum((xhat-yhat)^2) >= 0, errors scale
// with distance, no cancellation)
__global__ __launch_bounds__(64) void convert_kernel(
    const float* __restrict__ Xe, const float* __restrict__ Xz,
    _Float16* __restrict__ He, _Float16* __restrict__ Hz,
    float* __restrict__ sqe, float* __restrict__ sqz) {
  int row = blockIdx.x;
  const float* X = blockIdx.y ? Xz : Xe;
  _Float16* H = blockIdx.y ? Hz : He;
  float* sq = blockIdx.y ? sqz : sqe;
  int lane = threadIdx.x;
  float v0 = X[(size_t)row * DD + lane];
  float v1 = X[(size_t)row * DD + 64 + lane];
  _Float16 h0 = (_Float16)v0, h1 = (_Float16)v1;
  H[(size_t)row * DD + lane] = h0;
  H[(size_t)row * DD + 64 + lane] = h1;
  float f0 = (float)h0, f1 = (float)h1;
  float s = f0 * f0 + f1 * f1;
  for (int off = 32; off; off >>= 1) s += __shfl_down(s, off);
  if (lane == 0) sq[row] = s;
}

// ---------------------------------------------------------------------------
// fp16 MFMA gram -> distance matrices. Triangular 128x128 block decomposition
// (bx<=by), write tile and its transpose. blockIdx.z: 0 -> de, 1 -> dz.
__global__ __launch_bounds__(256, 2) void gram_kernel(
    const _Float16* __restrict__ He, const float* __restrict__ sqe,
    const _Float16* __restrict__ Hz, const float* __restrict__ sqz,
    float* __restrict__ de, float* __restrict__ dz) {
  __shared__ _Float16 sA[128 * 128];
  __shared__ _Float16 sB[128 * 128];
  int b = blockIdx.x;
  int by = (int)((sqrtf(8.0f * (float)b + 1.0f) - 1.0f) * 0.5f);
  while ((by + 1) * (by + 2) / 2 <= b) by++;
  while (by * (by + 1) / 2 > b) by--;
  int bx = b - by * (by + 1) / 2;  // bx <= by
  const _Float16* H = blockIdx.z ? Hz : He;
  const float* sq = blockIdx.z ? sqz : sqe;
  float* out = blockIdx.z ? dz : de;
  int I = bx * 128, J = by * 128;
  int t = threadIdx.x;

  // stage 128 rows x 128 fp16 per side; XOR-swizzle byte ^= (row&7)<<4
#pragma unroll
  for (int it = 0; it < 8; ++it) {
    int u = it * 256 + t;
    int r = u >> 4, c16 = u & 15;
    int byteoff = r * 256 + ((c16 * 16) ^ ((r & 7) << 4));
    float4 va = *reinterpret_cast<const float4*>(H + (size_t)(I + r) * DD + c16 * 8);
    *reinterpret_cast<float4*>((char*)sA + byteoff) = va;
    float4 vb = *reinterpret_cast<const float4*>(H + (size_t)(J + r) * DD + c16 * 8);
    *reinterpret_cast<float4*>((char*)sB + byteoff) = vb;
  }
  __syncthreads();

  int w = t >> 6, l = t & 63;
  int wr = (w >> 1) * 64, wc = (w & 1) * 64;
  f32x4 acc[4][4];
#pragma unroll
  for (int m = 0; m < 4; ++m)
#pragma unroll
    for (int n = 0; n < 4; ++n) {
      f32x4 zz = {0.f, 0.f, 0.f, 0.f};
      acc[m][n] = zz;
    }

#pragma unroll
  for (int kstep = 0; kstep < 4; ++kstep) {
    f16x8 a[4], bb[4];
    int colb = kstep * 64 + (l >> 4) * 16;
#pragma unroll
    for (int m = 0; m < 4; ++m) {
      int rr = wr + m * 16 + (l & 15);
      a[m] = *reinterpret_cast<const f16x8*>((char*)sA + rr * 256 + (colb ^ ((rr & 7) << 4)));
    }
#pragma unroll
    for (int n = 0; n < 4; ++n) {
      int rr = wc + n * 16 + (l & 15);
      bb[n] = *reinterpret_cast<const f16x8*>((char*)sB + rr * 256 + (colb ^ ((rr & 7) << 4)));
    }
#pragma unroll
    for (int m = 0; m < 4; ++m)
#pragma unroll
      for (int n = 0; n < 4; ++n)
        acc[m][n] = __builtin_amdgcn_mfma_f32_16x16x32_f16(a[m], bb[n], acc[m][n], 0, 0, 0);
  }

  int mode = blockIdx.z;
#pragma unroll
  for (int m = 0; m < 4; ++m) {
#pragma unroll
    for (int n = 0; n < 4; ++n) {
#pragma unroll
      for (int q = 0; q < 4; ++q) {
        int row = I + wr + m * 16 + (l >> 4) * 4 + q;
        int col = J + wc + n * 16 + (l & 15);
        float d2 = (row == col) ? 0.0f : (sq[row] + sq[col] - 2.0f * acc[m][n][q]);
        float d = sqrtf(fmaxf(d2, 0.0f) + 1e-12f);
        if (mode) d = sqrtf(d + 1e-9f);
        out[(size_t)row * NN + col] = d;
        out[(size_t)col * NN + row] = d;
      }
    }
  }
}

// ---------------------------------------------------------------------------
// fused row pass: stage de-row + dz-row in LDS once; compute rowmean(dz),
// 5th-smallest(de), dense partial sum, neighbor + reverse lists.
__global__ __launch_bounds__(256) void rowpass_kernel(
    const float* __restrict__ de, const float* __restrict__ dz,
    float* __restrict__ rmean, int* __restrict__ nbr, int* __restrict__ nbrcnt,
    int* __restrict__ rev, int* __restrict__ revcnt, double* __restrict__ acc) {
  __shared__ float lde[NN];
  __shared__ float ldz[NN];
  __shared__ double red[256];
  __shared__ float b5[256][5];
  __shared__ float skth;
  __shared__ float sinv;
  __shared__ int scnt;

  int row = blockIdx.x, t = threadIdx.x;
  if (t == 0) scnt = 0;
  const float4* pe = reinterpret_cast<const float4*>(de + (size_t)row * NN);
  const float4* pz = reinterpret_cast<const float4*>(dz + (size_t)row * NN);
  double zsum = 0.0;
  float best[5] = {3.4e38f, 3.4e38f, 3.4e38f, 3.4e38f, 3.4e38f};
  for (int c = t; c < NN / 4; c += 256) {
    float4 ve = pe[c];
    float4 vz = pz[c];
    *reinterpret_cast<float4*>(&lde[c * 4]) = ve;
    *reinterpret_cast<float4*>(&ldz[c * 4]) = vz;
    zsum += (double)vz.x + vz.y + vz.z + vz.w;
    float e4[4] = {ve.x, ve.y, ve.z, ve.w};
#pragma unroll
    for (int q4 = 0; q4 < 4; ++q4) {
      float v = e4[q4];
      if (v < best[4]) {
        best[4] = v;
#pragma unroll
        for (int q = 4; q > 0; --q)
          if (best[q] < best[q - 1]) {
            float tmp = best[q]; best[q] = best[q - 1]; best[q - 1] = tmp;
          }
      }
    }
  }
  red[t] = zsum;
#pragma unroll
  for (int q = 0; q < 5; ++q) b5[t][q] = best[q];
  __syncthreads();
  // rowmean tree + kth merge tree (same passes)
  for (int s = 128; s >= 1; s >>= 1) {
    if (t < s) {
      red[t] += red[t + s];
      float a[5], b[5], o[5];
#pragma unroll
      for (int q = 0; q < 5; ++q) { a[q] = b5[t][q]; b[q] = b5[t + s][q]; }
      int ia = 0, ib = 0;
#pragma unroll
      for (int q = 0; q < 5; ++q) o[q] = (a[ia] <= b[ib]) ? a[ia++] : b[ib++];
#pragma unroll
      for (int q = 0; q < 5; ++q) b5[t][q] = o[q];
    }
    __syncthreads();
  }
  if (t == 0) {
    float rm = (float)(red[0] / NN);
    rmean[row] = rm;
    sinv = 1.0f / rm;
    skth = b5[0][4];
  }
  __syncthreads();
  float kth = skth, inv = sinv;

  // dense sum + neighbor scan from LDS
  double s = 0.0;
  for (int c = t; c < NN; c += 256) {
    float e = lde[c];
    float del = ldz[c] * inv;
    float rr = fmaxf(1.0f - del, 0.0f);
    float a = del * del - rr * rr;
    s += (double)(0.5f * expf(-e) * a + rr * rr);
    if (e <= kth) {
      int p = atomicAdd(&scnt, 1);
      if (p < CAPN) nbr[row * CAPN + p] = c;
      int q = atomicAdd(&revcnt[c], 1);
      if (q < CAPR) rev[(size_t)c * CAPR + q] = row;
    }
  }
  red[t] = s;
  __syncthreads();
  for (int st = 128; st; st >>= 1) {
    if (t < st) red[t] += red[t + st];
    __syncthreads();
  }
  if (t == 0) {
    atomicAdd(&acc[row & 127], red[0]);
    nbrcnt[row] = min(scnt, CAPN);
  }
}

// ---------------------------------------------------------------------------
// mutual lists: mut[k] = {j : j in kNN(k) and k in kNN(j)}
__global__ __launch_bounds__(64) void mut_kernel(
    const int* __restrict__ nbr, const int* __restrict__ nbrcnt,
    int* __restrict__ mut, int* __restrict__ mutcnt) {
  int k = blockIdx.x;
  int lane = threadIdx.x;
  __shared__ int cnt;
  if (lane == 0) cnt = 0;
  __syncthreads();
  int ck = nbrcnt[k];
  if (lane < ck) {
    int j = nbr[k * CAPN + lane];
    int cj = nbrcnt[j];
    bool found = false;
    for (int q = 0; q < cj; ++q)
      if (nbr[j * CAPN + q] == k) { found = true; break; }
    if (found) {
      int p = atomicAdd(&cnt, 1);
      if (p < CAPM) mut[k * CAPM + p] = j;
    }
  }
  __syncthreads();
  if (lane == 0) mutcnt[k] = min(cnt, CAPM);
}

// ---------------------------------------------------------------------------
// sparse contribution: T = sum_{i,j} sim2[i,j]*abar[i,j]
__global__ __launch_bounds__(64) void sparse_kernel(
    const int* __restrict__ nbr, const int* __restrict__ nbrcnt,
    const int* __restrict__ rev, const int* __restrict__ revcnt,
    const int* __restrict__ mut, const int* __restrict__ mutcnt,
    const float* __restrict__ dz, const float* __restrict__ rowmean,
    double* __restrict__ acc) {
  int i = blockIdx.x, lane = threadIdx.x;
  int rm = revcnt[i];
  int rr = mutcnt[i];
  float inv_i = 1.0f / rowmean[i];
  const float* dzi = dz + (size_t)i * NN;
  double s = 0.0;
  int rcap = min(rm, CAPR);
  for (int li = lane; li < rcap; li += 64) {
    int l = rev[(size_t)i * CAPR + li];
    int cl = nbrcnt[l];
    for (int q = 0; q < cl; ++q) {
      int k = nbr[l * CAPN + q];
      int cm = mutcnt[k];
      for (int w = 0; w < cm; ++w) {
        int j = mut[k * CAPM + w];
        float dd = dzi[j];
        float d1 = dd * inv_i;           // delta[i,j]
        float d2 = dd / rowmean[j];      // delta[j,i]
        float r1 = fmaxf(1.0f - d1, 0.0f);
        float r2 = fmaxf(1.0f - d2, 0.0f);
        s += 0.5 * ((double)(d1 * d1 - r1 * r1) + (double)(d2 * d2 - r2 * r2));
      }
    }
  }
  for (int off = 32; off; off >>= 1) s += __shfl_down(s, off);
  if (lane == 0 && rm > 0 && rr > 0)
    atomicAdd(&acc[128 + (i & 127)], s / ((double)rm * (double)rr));
}

// ---------------------------------------------------------------------------
__global__ void init_kernel(int* __restrict__ revcnt, double* __restrict__ acc) {
  int t = blockIdx.x * 256 + threadIdx.x;
  if (t < NN) revcnt[t] = 0;
  if (t < 256) acc[t] = 0.0;
}

__global__ __launch_bounds__(256) void finalize_kernel(
    const double* __restrict__ acc, float* __restrict__ out) {
  __shared__ double red[256];
  int t = threadIdx.x;
  red[t] = acc[t] * ((t < 128) ? 1.0 : 0.5);
  __syncthreads();
  for (int st = 128; st; st >>= 1) {
    if (t < st) red[t] += red[t + st];
    __syncthreads();
  }
  if (t == 0) out[0] = (float)(red[0] / (double)NN);
}

// ---------------------------------------------------------------------------
extern "C" void kernel_launch(void* const* d_in, const int* in_sizes, int n_in,
                              void* d_out, int out_size, void* d_ws, size_t ws_size,
                              hipStream_t stream) {
  const float* z  = (const float*)d_in[0];
  const float* ze = (const float*)d_in[1];
  float* out = (float*)d_out;

  char* w = (char*)d_ws;
  size_t SZ = (size_t)NN * NN * 4;
  float* de = (float*)w;
  float* dz = (float*)(w + SZ);
  size_t off = 2 * SZ;
  _Float16* He = (_Float16*)(w + off); off += (size_t)NN * DD * 2;
  _Float16* Hz = (_Float16*)(w + off); off += (size_t)NN * DD * 2;
  float* sqe = (float*)(w + off); off += NN * 4;
  float* sqz = (float*)(w + off); off += NN * 4;
  float* rmean = (float*)(w + off); off += NN * 4;
  double* acc = (double*)(w + off); off += 256 * 8;
  int* nbrcnt = (int*)(w + off); off += NN * 4;
  int* mutcnt = (int*)(w + off); off += NN * 4;
  int* revcnt = (int*)(w + off); off += NN * 4;
  int* nbr = (int*)(w + off); off += (size_t)NN * CAPN * 4;
  int* mutl = (int*)(w + off); off += (size_t)NN * CAPM * 4;
  int* rev = (int*)(w + off); off += (size_t)NN * CAPR * 4;

  init_kernel<<<dim3((NN + 255) / 256), 256, 0, stream>>>(revcnt, acc);
  convert_kernel<<<dim3(NN, 2), 64, 0, stream>>>(ze, z, He, Hz, sqe, sqz);
  gram_kernel<<<dim3(528, 1, 2), 256, 0, stream>>>(He, sqe, Hz, sqz, de, dz);
  rowpass_kernel<<<NN, 256, 0, stream>>>(de, dz, rmean, nbr, nbrcnt, rev, revcnt, acc);
  mut_kernel<<<NN, 64, 0, stream>>>(nbr, nbrcnt, mutl, mutcnt);
  sparse_kernel<<<NN, 64, 0, stream>>>(nbr, nbrcnt, rev, revcnt, mutl, mutcnt,
                                       dz, rmean, acc);
  finalize_kernel<<<1, 256, 0, stream>>>(acc, out);
}

// Round 3
// 190.995 us; speedup vs baseline: 2.2231x; 1.0849x over previous
//
#include <hip/hip_runtime.h>
#include <hip/hip_bf16.h>
#include <math.h>

#define NN 4096
#define DD 128
#define CAPN 32
#define CAPM 32
#define CAPR 256

typedef _Float16 f16x8 __attribute__((ext_vector_type(8)));
typedef float f32x4 __attribute__((ext_vector_type(4)));

// ---------------------------------------------------------------------------
// convert f32 -> fp16 copies + sq norms computed FROM THE ROUNDED values
// (so d2 = sq_i + sq_j - 2*G_fp16 == sum((xhat-yhat)^2) >= 0, errors scale
// with distance, no cancellation)
__global__ __launch_bounds__(64) void convert_kernel(
    const float* __restrict__ Xe, const float* __restrict__ Xz,
    _Float16* __restrict__ He, _Float16* __restrict__ Hz,
    float* __restrict__ sqe, float* __restrict__ sqz) {
  int row = blockIdx.x;
  const float* X = blockIdx.y ? Xz : Xe;
  _Float16* H = blockIdx.y ? Hz : He;
  float* sq = blockIdx.y ? sqz : sqe;
  int lane = threadIdx.x;
  float v0 = X[(size_t)row * DD + lane];
  float v1 = X[(size_t)row * DD + 64 + lane];
  _Float16 h0 = (_Float16)v0, h1 = (_Float16)v1;
  H[(size_t)row * DD + lane] = h0;
  H[(size_t)row * DD + 64 + lane] = h1;
  float f0 = (float)h0, f1 = (float)h1;
  float s = f0 * f0 + f1 * f1;
  for (int off = 32; off; off >>= 1) s += __shfl_down(s, off);
  if (lane == 0) sq[row] = s;
}

// ---------------------------------------------------------------------------
// fp16 MFMA gram -> fp16 distance matrices. Triangular 128x128 block
// decomposition (bx<=by); tile + transpose staged in LDS, written coalesced.
// blockIdx.z: 0 -> de, 1 -> dz.
__global__ __launch_bounds__(256, 2) void gram_kernel(
    const _Float16* __restrict__ He, const float* __restrict__ sqe,
    const _Float16* __restrict__ Hz, const float* __restrict__ sqz,
    _Float16* __restrict__ de, _Float16* __restrict__ dz) {
  __shared__ _Float16 sA[128 * 128];
  __shared__ _Float16 sB[128 * 128];
  int b = blockIdx.x;
  int by = (int)((sqrtf(8.0f * (float)b + 1.0f) - 1.0f) * 0.5f);
  while ((by + 1) * (by + 2) / 2 <= b) by++;
  while (by * (by + 1) / 2 > b) by--;
  int bx = b - by * (by + 1) / 2;  // bx <= by
  const _Float16* H = blockIdx.z ? Hz : He;
  const float* sq = blockIdx.z ? sqz : sqe;
  _Float16* out = blockIdx.z ? dz : de;
  int I = bx * 128, J = by * 128;
  int t = threadIdx.x;

  // stage 128 rows x 128 fp16 per side; XOR-swizzle byte ^= (row&7)<<4
#pragma unroll
  for (int it = 0; it < 8; ++it) {
    int u = it * 256 + t;
    int r = u >> 4, c16 = u & 15;
    int byteoff = r * 256 + ((c16 * 16) ^ ((r & 7) << 4));
    float4 va = *reinterpret_cast<const float4*>(H + (size_t)(I + r) * DD + c16 * 8);
    *reinterpret_cast<float4*>((char*)sA + byteoff) = va;
    float4 vb = *reinterpret_cast<const float4*>(H + (size_t)(J + r) * DD + c16 * 8);
    *reinterpret_cast<float4*>((char*)sB + byteoff) = vb;
  }
  __syncthreads();

  int w = t >> 6, l = t & 63;
  int wr = (w >> 1) * 64, wc = (w & 1) * 64;
  f32x4 acc[4][4];
#pragma unroll
  for (int m = 0; m < 4; ++m)
#pragma unroll
    for (int n = 0; n < 4; ++n) {
      f32x4 zz = {0.f, 0.f, 0.f, 0.f};
      acc[m][n] = zz;
    }

#pragma unroll
  for (int kstep = 0; kstep < 4; ++kstep) {
    f16x8 a[4], bb[4];
    int colb = kstep * 64 + (l >> 4) * 16;
#pragma unroll
    for (int m = 0; m < 4; ++m) {
      int rr = wr + m * 16 + (l & 15);
      a[m] = *reinterpret_cast<const f16x8*>((char*)sA + rr * 256 + (colb ^ ((rr & 7) << 4)));
    }
#pragma unroll
    for (int n = 0; n < 4; ++n) {
      int rr = wc + n * 16 + (l & 15);
      bb[n] = *reinterpret_cast<const f16x8*>((char*)sB + rr * 256 + (colb ^ ((rr & 7) << 4)));
    }
#pragma unroll
    for (int m = 0; m < 4; ++m)
#pragma unroll
      for (int n = 0; n < 4; ++n)
        acc[m][n] = __builtin_amdgcn_mfma_f32_16x16x32_f16(a[m], bb[n], acc[m][n], 0, 0, 0);
  }

  __syncthreads();  // staging reads done; reuse sA/sB as output tiles
  _Float16* T = sA;   // tile, row-major (swizzled)
  _Float16* TT = sB;  // transposed tile (swizzled)
  int mode = blockIdx.z;
#pragma unroll
  for (int m = 0; m < 4; ++m) {
#pragma unroll
    for (int n = 0; n < 4; ++n) {
#pragma unroll
      for (int q = 0; q < 4; ++q) {
        int rt = wr + m * 16 + (l >> 4) * 4 + q;
        int ct = wc + n * 16 + (l & 15);
        int grow = I + rt, gcol = J + ct;
        float d2 = (grow == gcol) ? 0.0f : (sq[grow] + sq[gcol] - 2.0f * acc[m][n][q]);
        float d = sqrtf(fmaxf(d2, 0.0f) + 1e-12f);
        if (mode) d = sqrtf(d + 1e-9f);
        _Float16 h = (_Float16)d;
        *(_Float16*)((char*)T + rt * 256 + ((ct * 2) ^ ((rt & 7) << 4))) = h;
        if (bx != by)
          *(_Float16*)((char*)TT + ct * 256 + ((rt * 2) ^ ((ct & 7) << 4))) = h;
      }
    }
  }
  __syncthreads();
  // coalesced 16B global writes of tile rows (and transpose rows if off-diag)
  for (int u = t; u < 128 * 16; u += 256) {
    int r = u >> 4, cg = u & 15;
    float4 v = *reinterpret_cast<const float4*>(
        (char*)T + r * 256 + ((cg * 16) ^ ((r & 7) << 4)));
    *reinterpret_cast<float4*>((char*)out + ((size_t)(I + r) * NN + J) * 2 + cg * 16) = v;
    if (bx != by) {
      float4 v2 = *reinterpret_cast<const float4*>(
          (char*)TT + r * 256 + ((cg * 16) ^ ((r & 7) << 4)));
      *reinterpret_cast<float4*>((char*)out + ((size_t)(J + r) * NN + I) * 2 + cg * 16) = v2;
    }
  }
}

// ---------------------------------------------------------------------------
// fused row pass: stage de-row + dz-row (fp16) in LDS once; compute
// rowmean(dz), 5th-smallest(de), dense partial sum, neighbor + reverse lists.
__global__ __launch_bounds__(256) void rowpass_kernel(
    const _Float16* __restrict__ de, const _Float16* __restrict__ dz,
    float* __restrict__ rmean, int* __restrict__ nbr, int* __restrict__ nbrcnt,
    int* __restrict__ rev, int* __restrict__ revcnt, double* __restrict__ acc) {
  __shared__ _Float16 lde[NN];
  __shared__ _Float16 ldz[NN];
  __shared__ double red[256];
  __shared__ float b5[256][5];
  __shared__ float skth;
  __shared__ float sinv;
  __shared__ int scnt;

  int row = blockIdx.x, t = threadIdx.x;
  if (t == 0) scnt = 0;
  const float4* pe = reinterpret_cast<const float4*>(de + (size_t)row * NN);
  const float4* pz = reinterpret_cast<const float4*>(dz + (size_t)row * NN);
  double zsum = 0.0;
  float best[5] = {3.4e38f, 3.4e38f, 3.4e38f, 3.4e38f, 3.4e38f};
  for (int c = t; c < NN / 8; c += 256) {
    float4 ve = pe[c];
    float4 vz = pz[c];
    *reinterpret_cast<float4*>(&lde[c * 8]) = ve;
    *reinterpret_cast<float4*>(&ldz[c * 8]) = vz;
    const _Float16* he = reinterpret_cast<const _Float16*>(&ve);
    const _Float16* hz = reinterpret_cast<const _Float16*>(&vz);
#pragma unroll
    for (int q4 = 0; q4 < 8; ++q4) {
      zsum += (double)(float)hz[q4];
      float v = (float)he[q4];
      if (v < best[4]) {
        best[4] = v;
#pragma unroll
        for (int q = 4; q > 0; --q)
          if (best[q] < best[q - 1]) {
            float tmp = best[q]; best[q] = best[q - 1]; best[q - 1] = tmp;
          }
      }
    }
  }
  red[t] = zsum;
#pragma unroll
  for (int q = 0; q < 5; ++q) b5[t][q] = best[q];
  __syncthreads();
  // rowmean tree + kth merge tree (same passes)
  for (int s = 128; s >= 1; s >>= 1) {
    if (t < s) {
      red[t] += red[t + s];
      float a[5], b[5], o[5];
#pragma unroll
      for (int q = 0; q < 5; ++q) { a[q] = b5[t][q]; b[q] = b5[t + s][q]; }
      int ia = 0, ib = 0;
#pragma unroll
      for (int q = 0; q < 5; ++q) o[q] = (a[ia] <= b[ib]) ? a[ia++] : b[ib++];
#pragma unroll
      for (int q = 0; q < 5; ++q) b5[t][q] = o[q];
    }
    __syncthreads();
  }
  if (t == 0) {
    float rm = (float)(red[0] / NN);
    rmean[row] = rm;
    sinv = 1.0f / rm;
    skth = b5[0][4];
  }
  __syncthreads();
  float kth = skth, inv = sinv;

  // dense sum + neighbor scan from LDS
  double s = 0.0;
  for (int c = t; c < NN; c += 256) {
    float e = (float)lde[c];
    float del = (float)ldz[c] * inv;
    float rr = fmaxf(1.0f - del, 0.0f);
    float a = del * del - rr * rr;
    s += (double)(0.5f * expf(-e) * a + rr * rr);
    if (e <= kth) {
      int p = atomicAdd(&scnt, 1);
      if (p < CAPN) nbr[row * CAPN + p] = c;
      int q = atomicAdd(&revcnt[c], 1);
      if (q < CAPR) rev[(size_t)c * CAPR + q] = row;
    }
  }
  red[t] = s;
  __syncthreads();
  for (int st = 128; st; st >>= 1) {
    if (t < st) red[t] += red[t + st];
    __syncthreads();
  }
  if (t == 0) {
    atomicAdd(&acc[row & 127], red[0]);
    nbrcnt[row] = min(scnt, CAPN);
  }
}

// ---------------------------------------------------------------------------
// mutual lists: mut[k] = {j : j in kNN(k) and k in kNN(j)}
__global__ __launch_bounds__(64) void mut_kernel(
    const int* __restrict__ nbr, const int* __restrict__ nbrcnt,
    int* __restrict__ mut, int* __restrict__ mutcnt) {
  int k = blockIdx.x;
  int lane = threadIdx.x;
  __shared__ int cnt;
  if (lane == 0) cnt = 0;
  __syncthreads();
  int ck = nbrcnt[k];
  if (lane < ck) {
    int j = nbr[k * CAPN + lane];
    int cj = nbrcnt[j];
    bool found = false;
    for (int q = 0; q < cj; ++q)
      if (nbr[j * CAPN + q] == k) { found = true; break; }
    if (found) {
      int p = atomicAdd(&cnt, 1);
      if (p < CAPM) mut[k * CAPM + p] = j;
    }
  }
  __syncthreads();
  if (lane == 0) mutcnt[k] = min(cnt, CAPM);
}

// ---------------------------------------------------------------------------
// sparse contribution: T = sum_{i,j} sim2[i,j]*abar[i,j]
__global__ __launch_bounds__(64) void sparse_kernel(
    const int* __restrict__ nbr, const int* __restrict__ nbrcnt,
    const int* __restrict__ rev, const int* __restrict__ revcnt,
    const int* __restrict__ mut, const int* __restrict__ mutcnt,
    const _Float16* __restrict__ dz, const float* __restrict__ rowmean,
    double* __restrict__ acc) {
  int i = blockIdx.x, lane = threadIdx.x;
  int rm = revcnt[i];
  int rr = mutcnt[i];
  float inv_i = 1.0f / rowmean[i];
  const _Float16* dzi = dz + (size_t)i * NN;
  double s = 0.0;
  int rcap = min(rm, CAPR);
  for (int li = lane; li < rcap; li += 64) {
    int l = rev[(size_t)i * CAPR + li];
    int cl = nbrcnt[l];
    for (int q = 0; q < cl; ++q) {
      int k = nbr[l * CAPN + q];
      int cm = mutcnt[k];
      for (int w = 0; w < cm; ++w) {
        int j = mut[k * CAPM + w];
        float dd = (float)dzi[j];
        float d1 = dd * inv_i;           // delta[i,j]
        float d2 = dd / rowmean[j];      // delta[j,i]
        float r1 = fmaxf(1.0f - d1, 0.0f);
        float r2 = fmaxf(1.0f - d2, 0.0f);
        s += 0.5 * ((double)(d1 * d1 - r1 * r1) + (double)(d2 * d2 - r2 * r2));
      }
    }
  }
  for (int off = 32; off; off >>= 1) s += __shfl_down(s, off);
  if (lane == 0 && rm > 0 && rr > 0)
    atomicAdd(&acc[128 + (i & 127)], s / ((double)rm * (double)rr));
}

// ---------------------------------------------------------------------------
__global__ void init_kernel(int* __restrict__ revcnt, double* __restrict__ acc) {
  int t = blockIdx.x * 256 + threadIdx.x;
  if (t < NN) revcnt[t] = 0;
  if (t < 256) acc[t] = 0.0;
}

__global__ __launch_bounds__(256) void finalize_kernel(
    const double* __restrict__ acc, float* __restrict__ out) {
  __shared__ double red[256];
  int t = threadIdx.x;
  red[t] = acc[t] * ((t < 128) ? 1.0 : 0.5);
  __syncthreads();
  for (int st = 128; st; st >>= 1) {
    if (t < st) red[t] += red[t + st];
    __syncthreads();
  }
  if (t == 0) out[0] = (float)(red[0] / (double)NN);
}

// ---------------------------------------------------------------------------
extern "C" void kernel_launch(void* const* d_in, const int* in_sizes, int n_in,
                              void* d_out, int out_size, void* d_ws, size_t ws_size,
                              hipStream_t stream) {
  const float* z  = (const float*)d_in[0];
  const float* ze = (const float*)d_in[1];
  float* out = (float*)d_out;

  char* w = (char*)d_ws;
  size_t SZ = (size_t)NN * NN * 2;  // fp16 matrices
  _Float16* de = (_Float16*)w;
  _Float16* dz = (_Float16*)(w + SZ);
  size_t off = 2 * SZ;
  _Float16* He = (_Float16*)(w + off); off += (size_t)NN * DD * 2;
  _Float16* Hz = (_Float16*)(w + off); off += (size_t)NN * DD * 2;
  float* sqe = (float*)(w + off); off += NN * 4;
  float* sqz = (float*)(w + off); off += NN * 4;
  float* rmean = (float*)(w + off); off += NN * 4;
  double* acc = (double*)(w + off); off += 256 * 8;
  int* nbrcnt = (int*)(w + off); off += NN * 4;
  int* mutcnt = (int*)(w + off); off += NN * 4;
  int* revcnt = (int*)(w + off); off += NN * 4;
  int* nbr = (int*)(w + off); off += (size_t)NN * CAPN * 4;
  int* mutl = (int*)(w + off); off += (size_t)NN * CAPM * 4;
  int* rev = (int*)(w + off); off += (size_t)NN * CAPR * 4;

  init_kernel<<<dim3((NN + 255) / 256), 256, 0, stream>>>(revcnt, acc);
  convert_kernel<<<dim3(NN, 2), 64, 0, stream>>>(ze, z, He, Hz, sqe, sqz);
  gram_kernel<<<dim3(528, 1, 2), 256, 0, stream>>>(He, sqe, Hz, sqz, de, dz);
  rowpass_kernel<<<NN, 256, 0, stream>>>(de, dz, rmean, nbr, nbrcnt, rev, revcnt, acc);
  mut_kernel<<<NN, 64, 0, stream>>>(nbr, nbrcnt, mutl, mutcnt);
  sparse_kernel<<<NN, 64, 0, stream>>>(nbr, nbrcnt, rev, revcnt, mutl, mutcnt,
                                       dz, rmean, acc);
  finalize_kernel<<<1, 256, 0, stream>>>(acc, out);
}

// Round 4
// 143.220 us; speedup vs baseline: 2.9647x; 1.3336x over previous
//
#include <hip/hip_runtime.h>
#include <hip/hip_bf16.h>
#include <math.h>

#define NN 4096
#define DD 128
#define CAPN 32
#define CAPM 32

typedef _Float16 f16x8 __attribute__((ext_vector_type(8)));
typedef float f32x4 __attribute__((ext_vector_type(4)));

// ---------------------------------------------------------------------------
// convert f32 -> fp16 copies + sq norms from the ROUNDED values; folds the
// zero-init of revcnt/acc (re-poisoned workspace each launch).
__global__ __launch_bounds__(64) void convert_kernel(
    const float* __restrict__ Xe, const float* __restrict__ Xz,
    _Float16* __restrict__ He, _Float16* __restrict__ Hz,
    float* __restrict__ sqe, float* __restrict__ sqz,
    int* __restrict__ revcnt, double* __restrict__ acc) {
  int row = blockIdx.x;
  int lane = threadIdx.x;
  const float* X = blockIdx.y ? Xz : Xe;
  _Float16* H = blockIdx.y ? Hz : He;
  float* sq = blockIdx.y ? sqz : sqe;
  if (blockIdx.y == 0 && lane == 0) {
    revcnt[row] = 0;
    if (row < 256) acc[row] = 0.0;
  }
  float v0 = X[(size_t)row * DD + lane];
  float v1 = X[(size_t)row * DD + 64 + lane];
  _Float16 h0 = (_Float16)v0, h1 = (_Float16)v1;
  H[(size_t)row * DD + lane] = h0;
  H[(size_t)row * DD + 64 + lane] = h1;
  float f0 = (float)h0, f1 = (float)h1;
  float s = f0 * f0 + f1 * f1;
  for (int off = 32; off; off >>= 1) s += __shfl_down(s, off);
  if (lane == 0) sq[row] = s;
}

// ---------------------------------------------------------------------------
// fp16 MFMA gram -> distances. Triangular 128x128 blocks (bx<=by).
// mode 0: de (f32) — direct coalesced row-major store + LDS f32 transpose.
// mode 1: dz (fp16) — both orientations restaged through LDS.
__global__ __launch_bounds__(256, 2) void gram_kernel(
    const _Float16* __restrict__ He, const float* __restrict__ sqe,
    const _Float16* __restrict__ Hz, const float* __restrict__ sqz,
    float* __restrict__ de, _Float16* __restrict__ dz) {
  __shared__ char smem[65536];
  int b = blockIdx.x;
  int by = (int)((sqrtf(8.0f * (float)b + 1.0f) - 1.0f) * 0.5f);
  while ((by + 1) * (by + 2) / 2 <= b) by++;
  while (by * (by + 1) / 2 > b) by--;
  int bx = b - by * (by + 1) / 2;  // bx <= by
  int mode = blockIdx.z;
  const _Float16* H = mode ? Hz : He;
  const float* sq = mode ? sqz : sqe;
  int I = bx * 128, J = by * 128;
  int t = threadIdx.x;

  // stage 128 rows x 128 fp16 per side; XOR-swizzle byte ^= (row&7)<<4
#pragma unroll
  for (int it = 0; it < 8; ++it) {
    int u = it * 256 + t;
    int r = u >> 4, c16 = u & 15;
    int byteoff = r * 256 + ((c16 * 16) ^ ((r & 7) << 4));
    *reinterpret_cast<float4*>(smem + byteoff) =
        *reinterpret_cast<const float4*>(H + (size_t)(I + r) * DD + c16 * 8);
    *reinterpret_cast<float4*>(smem + 32768 + byteoff) =
        *reinterpret_cast<const float4*>(H + (size_t)(J + r) * DD + c16 * 8);
  }
  __syncthreads();

  int w = t >> 6, l = t & 63;
  int wr = (w >> 1) * 64, wc = (w & 1) * 64;
  f32x4 acc[4][4];
#pragma unroll
  for (int m = 0; m < 4; ++m)
#pragma unroll
    for (int n = 0; n < 4; ++n) {
      f32x4 zz = {0.f, 0.f, 0.f, 0.f};
      acc[m][n] = zz;
    }

#pragma unroll
  for (int kstep = 0; kstep < 4; ++kstep) {
    f16x8 a[4], bb[4];
    int colb = kstep * 64 + (l >> 4) * 16;
#pragma unroll
    for (int m = 0; m < 4; ++m) {
      int rr = wr + m * 16 + (l & 15);
      a[m] = *reinterpret_cast<const f16x8*>(smem + rr * 256 + (colb ^ ((rr & 7) << 4)));
    }
#pragma unroll
    for (int n = 0; n < 4; ++n) {
      int rr = wc + n * 16 + (l & 15);
      bb[n] = *reinterpret_cast<const f16x8*>(smem + 32768 + rr * 256 + (colb ^ ((rr & 7) << 4)));
    }
#pragma unroll
    for (int m = 0; m < 4; ++m)
#pragma unroll
      for (int n = 0; n < 4; ++n)
        acc[m][n] = __builtin_amdgcn_mfma_f32_16x16x32_f16(a[m], bb[n], acc[m][n], 0, 0, 0);
  }
  __syncthreads();  // staging reads done; reuse smem

  if (mode == 0) {
    // ---- de (f32): direct row-major store; transpose via 64KB f32 LDS tile
#pragma unroll
    for (int m = 0; m < 4; ++m) {
#pragma unroll
      for (int n = 0; n < 4; ++n) {
#pragma unroll
        for (int q = 0; q < 4; ++q) {
          int rt = wr + m * 16 + (l >> 4) * 4 + q;
          int ct = wc + n * 16 + (l & 15);
          int grow = I + rt, gcol = J + ct;
          float d2 = (grow == gcol) ? 0.0f : (sq[grow] + sq[gcol] - 2.0f * acc[m][n][q]);
          float d = __builtin_amdgcn_sqrtf(fmaxf(d2, 0.0f) + 1e-12f);
          de[(size_t)grow * NN + gcol] = d;
          if (bx != by)
            *reinterpret_cast<float*>(smem + ct * 512 + ((rt * 4) ^ ((ct & 7) << 4))) = d;
        }
      }
    }
    __syncthreads();
    if (bx != by) {
      for (int u = t; u < 128 * 32; u += 256) {
        int r = u >> 5, cg = u & 31;
        float4 v = *reinterpret_cast<const float4*>(
            smem + r * 512 + ((cg * 16) ^ ((r & 7) << 4)));
        *reinterpret_cast<float4*>((char*)de + ((size_t)(J + r) * NN + I) * 4 + cg * 16) = v;
      }
    }
  } else {
    // ---- dz (fp16): tile + transpose staged in LDS, written coalesced
#pragma unroll
    for (int m = 0; m < 4; ++m) {
#pragma unroll
      for (int n = 0; n < 4; ++n) {
#pragma unroll
        for (int q = 0; q < 4; ++q) {
          int rt = wr + m * 16 + (l >> 4) * 4 + q;
          int ct = wc + n * 16 + (l & 15);
          int grow = I + rt, gcol = J + ct;
          float d2 = (grow == gcol) ? 0.0f : (sq[grow] + sq[gcol] - 2.0f * acc[m][n][q]);
          float d = __builtin_amdgcn_sqrtf(fmaxf(d2, 0.0f) + 1e-12f);
          d = __builtin_amdgcn_sqrtf(d + 1e-9f);
          _Float16 h = (_Float16)d;
          *reinterpret_cast<_Float16*>(smem + rt * 256 + ((ct * 2) ^ ((rt & 7) << 4))) = h;
          if (bx != by)
            *reinterpret_cast<_Float16*>(smem + 32768 + ct * 256 + ((rt * 2) ^ ((ct & 7) << 4))) = h;
        }
      }
    }
    __syncthreads();
    for (int u = t; u < 128 * 16; u += 256) {
      int r = u >> 4, cg = u & 15;
      float4 v = *reinterpret_cast<const float4*>(
          smem + r * 256 + ((cg * 16) ^ ((r & 7) << 4)));
      *reinterpret_cast<float4*>((char*)dz + ((size_t)(I + r) * NN + J) * 2 + cg * 16) = v;
      if (bx != by) {
        float4 v2 = *reinterpret_cast<const float4*>(
            smem + 32768 + r * 256 + ((cg * 16) ^ ((r & 7) << 4)));
        *reinterpret_cast<float4*>((char*)dz + ((size_t)(J + r) * NN + I) * 2 + cg * 16) = v2;
      }
    }
  }
}

// ---------------------------------------------------------------------------
// fused row pass: stage de-row (f32) + dz-row (fp16) in LDS once; compute
// rowmean(dz), 5th-smallest(de), dense partial sum, nbr lists + revcnt.
__global__ __launch_bounds__(256) void rowpass_kernel(
    const float* __restrict__ de, const _Float16* __restrict__ dz,
    float* __restrict__ rminv, int* __restrict__ nbr, int* __restrict__ nbrcnt,
    int* __restrict__ revcnt, double* __restrict__ acc) {
  __shared__ float lde[NN];       // 16 KB
  __shared__ _Float16 ldz[NN];    // 8 KB
  __shared__ double red[256];
  __shared__ float b5[256][5];
  __shared__ float skth;
  __shared__ float sinv;
  __shared__ int scnt;

  int row = blockIdx.x, t = threadIdx.x;
  if (t == 0) scnt = 0;
  const float4* pe = reinterpret_cast<const float4*>(de + (size_t)row * NN);
  const float4* pz = reinterpret_cast<const float4*>(dz + (size_t)row * NN);
  double zsum = 0.0;
  float best[5] = {3.4e38f, 3.4e38f, 3.4e38f, 3.4e38f, 3.4e38f};
  for (int c = t; c < NN / 8; c += 256) {
    float4 e0 = pe[c * 2];
    float4 e1 = pe[c * 2 + 1];
    float4 vz = pz[c];
    *reinterpret_cast<float4*>(&lde[c * 8]) = e0;
    *reinterpret_cast<float4*>(&lde[c * 8 + 4]) = e1;
    *reinterpret_cast<float4*>(&ldz[c * 8]) = vz;
    float ev[8] = {e0.x, e0.y, e0.z, e0.w, e1.x, e1.y, e1.z, e1.w};
    const _Float16* hz = reinterpret_cast<const _Float16*>(&vz);
#pragma unroll
    for (int q4 = 0; q4 < 8; ++q4) {
      zsum += (double)(float)hz[q4];
      float v = ev[q4];
      if (v < best[4]) {
        best[4] = v;
#pragma unroll
        for (int q = 4; q > 0; --q)
          if (best[q] < best[q - 1]) {
            float tmp = best[q]; best[q] = best[q - 1]; best[q - 1] = tmp;
          }
      }
    }
  }
  red[t] = zsum;
#pragma unroll
  for (int q = 0; q < 5; ++q) b5[t][q] = best[q];
  __syncthreads();
  for (int s = 128; s >= 1; s >>= 1) {
    if (t < s) {
      red[t] += red[t + s];
      float a[5], b[5], o[5];
#pragma unroll
      for (int q = 0; q < 5; ++q) { a[q] = b5[t][q]; b[q] = b5[t + s][q]; }
      int ia = 0, ib = 0;
#pragma unroll
      for (int q = 0; q < 5; ++q) o[q] = (a[ia] <= b[ib]) ? a[ia++] : b[ib++];
#pragma unroll
      for (int q = 0; q < 5; ++q) b5[t][q] = o[q];
    }
    __syncthreads();
  }
  if (t == 0) {
    float rm = (float)(red[0] / NN);
    float iv = 1.0f / rm;
    rminv[row] = iv;
    sinv = iv;
    skth = b5[0][4];
  }
  __syncthreads();
  float kth = skth, inv = sinv;

  // dense sum + neighbor scan from LDS
  double s = 0.0;
  for (int c = t; c < NN; c += 256) {
    float e = lde[c];
    float del = (float)ldz[c] * inv;
    float rr = fmaxf(1.0f - del, 0.0f);
    float a = del * del - rr * rr;
    s += (double)(0.5f * __expf(-e) * a + rr * rr);
    if (e <= kth) {
      int p = atomicAdd(&scnt, 1);
      if (p < CAPN) nbr[row * CAPN + p] = c;
      atomicAdd(&revcnt[c], 1);
    }
  }
  red[t] = s;
  __syncthreads();
  for (int st = 128; st; st >>= 1) {
    if (t < st) red[t] += red[t + st];
    __syncthreads();
  }
  if (t == 0) {
    atomicAdd(&acc[row & 127], red[0]);
    nbrcnt[row] = min(scnt, CAPN);
  }
}

// ---------------------------------------------------------------------------
// mutual lists: mut[k] = {j : j in kNN(k) and k in kNN(j)}
__global__ __launch_bounds__(64) void mut_kernel(
    const int* __restrict__ nbr, const int* __restrict__ nbrcnt,
    int* __restrict__ mut, int* __restrict__ mutcnt) {
  int k = blockIdx.x;
  int lane = threadIdx.x;
  __shared__ int cnt;
  if (lane == 0) cnt = 0;
  __syncthreads();
  int ck = nbrcnt[k];
  if (lane < ck) {
    int j = nbr[k * CAPN + lane];
    int cj = nbrcnt[j];
    bool found = false;
    for (int q = 0; q < cj; ++q)
      if (nbr[j * CAPN + q] == k) { found = true; break; }
    if (found) {
      int p = atomicAdd(&cnt, 1);
      if (p < CAPM) mut[k * CAPM + p] = j;
    }
  }
  __syncthreads();
  if (lane == 0) mutcnt[k] = min(cnt, CAPM);
}

// ---------------------------------------------------------------------------
// sparse: T = sum_n sum_{i,k in kNN(n)^2} c_i sum_{j in mut(k)} abar[i,j]
// (forward form — no reverse lists needed; c_i = 1/(revcnt_i * mutcnt_i))
__global__ __launch_bounds__(64) void sparse_kernel(
    const int* __restrict__ nbr, const int* __restrict__ nbrcnt,
    const int* __restrict__ revcnt, const int* __restrict__ mut,
    const int* __restrict__ mutcnt, const _Float16* __restrict__ dz,
    const float* __restrict__ rminv, double* __restrict__ acc) {
  int l = blockIdx.x, lane = threadIdx.x;
  int cl = nbrcnt[l];
  int npairs = cl * cl;
  double s = 0.0;
  for (int p = lane; p < npairs; p += 64) {
    int i = nbr[l * CAPN + p / cl];
    int k = nbr[l * CAPN + p % cl];
    float ci = 1.0f / ((float)revcnt[i] * (float)mutcnt[i]);
    float inv_i = rminv[i];
    const _Float16* dzi = dz + (size_t)i * NN;
    int cm = mutcnt[k];
    float ps = 0.0f;
    for (int w2 = 0; w2 < cm; ++w2) {
      int j = mut[k * CAPM + w2];
      float dd = (float)dzi[j];
      float d1 = dd * inv_i;
      float d2v = dd * rminv[j];
      float r1 = fmaxf(1.0f - d1, 0.0f);
      float r2 = fmaxf(1.0f - d2v, 0.0f);
      ps += 0.5f * ((d1 * d1 - r1 * r1) + (d2v * d2v - r2 * r2));
    }
    s += (double)ci * (double)ps;
  }
  for (int off = 32; off; off >>= 1) s += __shfl_down(s, off);
  if (lane == 0) atomicAdd(&acc[128 + (l & 127)], s);
}

// ---------------------------------------------------------------------------
__global__ __launch_bounds__(256) void finalize_kernel(
    const double* __restrict__ acc, float* __restrict__ out) {
  __shared__ double red[256];
  int t = threadIdx.x;
  red[t] = acc[t] * ((t < 128) ? 1.0 : 0.5);
  __syncthreads();
  for (int st = 128; st; st >>= 1) {
    if (t < st) red[t] += red[t + st];
    __syncthreads();
  }
  if (t == 0) out[0] = (float)(red[0] / (double)NN);
}

// ---------------------------------------------------------------------------
extern "C" void kernel_launch(void* const* d_in, const int* in_sizes, int n_in,
                              void* d_out, int out_size, void* d_ws, size_t ws_size,
                              hipStream_t stream) {
  const float* z  = (const float*)d_in[0];
  const float* ze = (const float*)d_in[1];
  float* out = (float*)d_out;

  char* w = (char*)d_ws;
  float* de = (float*)w;                               // 64 MiB f32
  size_t off = (size_t)NN * NN * 4;
  _Float16* dz = (_Float16*)(w + off); off += (size_t)NN * NN * 2;  // 32 MiB fp16
  _Float16* He = (_Float16*)(w + off); off += (size_t)NN * DD * 2;
  _Float16* Hz = (_Float16*)(w + off); off += (size_t)NN * DD * 2;
  float* sqe = (float*)(w + off); off += NN * 4;
  float* sqz = (float*)(w + off); off += NN * 4;
  float* rminv = (float*)(w + off); off += NN * 4;
  double* acc = (double*)(w + off); off += 256 * 8;
  int* nbrcnt = (int*)(w + off); off += NN * 4;
  int* mutcnt = (int*)(w + off); off += NN * 4;
  int* revcnt = (int*)(w + off); off += NN * 4;
  int* nbr = (int*)(w + off); off += (size_t)NN * CAPN * 4;
  int* mutl = (int*)(w + off); off += (size_t)NN * CAPM * 4;

  convert_kernel<<<dim3(NN, 2), 64, 0, stream>>>(ze, z, He, Hz, sqe, sqz,
                                                 revcnt, acc);
  gram_kernel<<<dim3(528, 1, 2), 256, 0, stream>>>(He, sqe, Hz, sqz, de, dz);
  rowpass_kernel<<<NN, 256, 0, stream>>>(de, dz, rminv, nbr, nbrcnt, revcnt, acc);
  mut_kernel<<<NN, 64, 0, stream>>>(nbr, nbrcnt, mutl, mutcnt);
  sparse_kernel<<<NN, 64, 0, stream>>>(nbr, nbrcnt, revcnt, mutl, mutcnt,
                                       dz, rminv, acc);
  finalize_kernel<<<1, 256, 0, stream>>>(acc, out);
}